// Round 4
// baseline (465.544 us; speedup 1.0000x reference)
//
#include <hip/hip_runtime.h>
#include <hip/hip_bf16.h>

// Problem: B=16, C=64, H=256, W=256, P=2
// y = haar2d_inv( sum_p softthr( (haar2d(x)*v_p) @ w_p^T, tau_p ) ) + x
//
// ws layout: bf16 (b, c, w_ref, h) transposed buffer (128 MiB) + bf16 weights
//            (2x64x64) at element offset 64Mi.
//   k_prep : conv_w f32 -> bf16 (one-time, 32 KiB)
//   k_fwdW : x(f32) -> Hw(x), transposed+subband-permuted bf16 store to ws
//   k_mid  : per (b,w) slab: Hh fwd (bf16 LDS, packed L1+2) -> MFMA mix ->
//            Hh inv -> bf16 store in place. 32 KiB LDS, 4 blocks/CU.
//   k_invW : ws -> Hw^{-1} + x -> y (f32, natural layout)

namespace {

constexpr float kNorm = 0.70710678118654752440f;

typedef __attribute__((ext_vector_type(8))) short short8;
typedef __attribute__((ext_vector_type(4))) float f32x4;
typedef __attribute__((ext_vector_type(8))) unsigned short ushort8;

// in-place lifting position -> reference subband position (n=256, 8 levels)
__device__ __forceinline__ int ip2ref(int p) {
  if (p == 0) return 0;
  const int j = __builtin_ctz(p) + 1;
  return (256 >> j) + (p >> j);
}
// reference subband position -> in-place lifting position
__device__ __forceinline__ int ref2ip(int r) {
  if (r == 0) return 0;
  const int tb = 31 - __builtin_clz(r);
  const int j = 8 - tb;
  return ((r - (1 << tb)) << j) | (1 << (j - 1));
}

__device__ __forceinline__ unsigned short f2bf(float f) {  // f32->bf16 RN
  unsigned int u = __float_as_uint(f);
  u += 0x7FFFu + ((u >> 16) & 1u);
  return (unsigned short)(u >> 16);
}
__device__ __forceinline__ float bf2f(unsigned int u) {
  return __uint_as_float((u & 0xFFFFu) << 16);
}
__device__ __forceinline__ unsigned pk2(float lo, float hi) {
  return (unsigned)f2bf(lo) | ((unsigned)f2bf(hi) << 16);
}

// ---------------- Kernel 0: conv_w f32 -> bf16 ------------------------------
__global__ __launch_bounds__(256) void k_prep(const float* __restrict__ cw,
                                              unsigned short* __restrict__ wb) {
  const int i = blockIdx.x * 256 + threadIdx.x;
  if (i < 8192) wb[i] = f2bf(cw[i]);
}

// ---------------- Kernel 1: forward Haar along W, transposed bf16 store -----
__global__ __launch_bounds__(256) void k_fwdW(const float* __restrict__ x,
                                              unsigned short* __restrict__ xt) {
  __shared__ float tile[32][257];  // 32 rows (h) x 256 cols (w), pitch 257
  const int blk = blockIdx.x;      // img*8 + htile
  const int img = blk >> 3;        // b*64 + c
  const int h0 = (blk & 7) << 5;
  const int tid = threadIdx.x;

  const float* __restrict__ src = x + ((size_t)img << 16) + ((size_t)h0 << 8);
#pragma unroll
  for (int j = 0; j < 32; ++j) tile[j][tid] = src[(j << 8) + tid];
  __syncthreads();

#pragma unroll
  for (int ls = 1; ls <= 8; ++ls) {
    const int s = 1 << ls;
    const int hs = s >> 1;
    const int ppr = 256 >> ls;
    const int total = 32 * ppr;
    for (int idx = tid; idx < total; idx += 256) {
      const int r = idx / ppr;
      const int i = idx - r * ppr;
      float* row = &tile[r][0];
      const int p0 = i * s;
      const float e = row[p0];
      const float o = row[p0 + hs];
      row[p0] = kNorm * (e + o);
      row[p0 + hs] = kNorm * (e - o);
    }
    __syncthreads();
  }

  // transposed bf16 write with in-place -> subband permutation: xt[img][wref][h]
  const int g8 = tid >> 5;
  const int l = tid & 31;
  unsigned short* __restrict__ dst = xt + ((size_t)img << 16) + h0;
#pragma unroll
  for (int k = 0; k < 32; ++k) {
    const int wp = g8 + (k << 3);
    const int wr = ip2ref(wp);
    dst[((size_t)wr << 8) + l] = f2bf(tile[l][wp]);
  }
}

// ---------------- Kernel 2: Hh fwd + MFMA mix + Hh inv (bf16 LDS) -----------
// LDS even-rotation swizzle: elem(c,h) = c*256 + ((h + 2c) & 255).
//  - Haar scalar access (c-fastest lanes): bank=(h/2 + c)&31 -> <=2-way.
//  - levels 1+2 / inverse 2+1 run packed (bf16x2 dwords, aligned since rot even)
__device__ __forceinline__ int swz2(int c, int h) {
  return (c << 8) | ((h + 2 * c) & 255);
}

__global__ __launch_bounds__(256, 4) void k_mid(unsigned short* __restrict__ ws,
                                                const float* __restrict__ vv,
                                                const unsigned short* __restrict__ wb,
                                                const float* __restrict__ tt) {
  __shared__ unsigned short tile[16384];  // 32 KiB: 64 c x 256 h, swizzled
  unsigned int* tile32 = reinterpret_cast<unsigned int*>(tile);
  const int blk = blockIdx.x;  // b*256 + w
  const int b = blk >> 8;
  const int w = blk & 255;
  const int tid = threadIdx.x;

  unsigned short* __restrict__ base = ws + ((size_t)b << 22) + ((size_t)w << 8);

  // ---- slab load: c=(tid&7)+8i, h0=8*(tid>>3): 128B-coalesced global,
  //      conflict-free LDS (bank = h0/2 + c + j = <=2-way across 32 lanes) ----
  const int cB = tid & 7;
  const int h0s = (tid >> 3) << 3;  // 0..248
#pragma unroll
  for (int i = 0; i < 8; ++i) {
    const int c = cB + (i << 3);
    const ushort8 raw =
        *reinterpret_cast<const ushort8*>(base + ((size_t)c << 16) + h0s);
#pragma unroll
    for (int j = 0; j < 4; ++j) {
      tile32[swz2(c, h0s + 2 * j) >> 1] =
          (unsigned)raw[2 * j] | ((unsigned)raw[2 * j + 1] << 16);
    }
  }
  __syncthreads();

  // ---- forward Haar along h: levels 1+2 packed (1 LDS op / 2 values) ----
#pragma unroll
  for (int it = 0; it < 16; ++it) {
    const int idx = tid + (it << 8);
    const int c = idx & 63;
    const int q = idx >> 6;
    const int p0 = q << 2;
    const unsigned dA = tile32[swz2(c, p0) >> 1];      // (e0,o0) @ p0,p0+1
    const unsigned dB = tile32[swz2(c, p0 + 2) >> 1];  // (e1,o1) @ p0+2,p0+3
    const float e0 = bf2f(dA), o0 = bf2f(dA >> 16);
    const float e1 = bf2f(dB), o1 = bf2f(dB >> 16);
    const float a0 = kNorm * (e0 + o0), dt0 = kNorm * (e0 - o0);
    const float a1 = kNorm * (e1 + o1), dt1 = kNorm * (e1 - o1);
    tile32[swz2(c, p0) >> 1]     = pk2(kNorm * (a0 + a1), dt0);
    tile32[swz2(c, p0 + 2) >> 1] = pk2(kNorm * (a0 - a1), dt1);
  }
  __syncthreads();

  // ---- forward Haar levels (3,4),(5,6),(7,8): scalar u16 quad lifting ----
#pragma unroll
  for (int ls = 3; ls <= 7; ls += 2) {
    const int s = 1 << ls;
    const int hs = s >> 1;
    const int s2 = s << 1;
    const int total = (128 >> ls) << 6;
    for (int idx = tid; idx < total; idx += 256) {
      const int c = idx & 63;
      const int q = idx >> 6;
      const int p0 = q * s2;
      const float e0 = bf2f(tile[swz2(c, p0)]);
      const float o0 = bf2f(tile[swz2(c, p0 + hs)]);
      const float e1 = bf2f(tile[swz2(c, p0 + s)]);
      const float o1 = bf2f(tile[swz2(c, p0 + s + hs)]);
      const float a0 = kNorm * (e0 + o0), dt0 = kNorm * (e0 - o0);
      const float a1 = kNorm * (e1 + o1), dt1 = kNorm * (e1 - o1);
      tile[swz2(c, p0)]          = f2bf(kNorm * (a0 + a1));
      tile[swz2(c, p0 + s)]      = f2bf(kNorm * (a0 - a1));
      tile[swz2(c, p0 + hs)]     = f2bf(dt0);
      tile[swz2(c, p0 + s + hs)] = f2bf(dt1);
    }
    __syncthreads();
  }

  // ---- A-fragment preload (bf16 already; no converts) ----
  // mfma_f32_16x16x32_bf16 A[m][k]: m=lane&15, k=8*(lane>>4)+j
  const int strip = (tid >> 6) << 6;  // wave id * 64 (h strip)
  const int l15 = tid & 15;
  const int l4 = (tid & 63) >> 4;
  short8 afr[2][4];
#pragma unroll
  for (int kt = 0; kt < 2; ++kt)
#pragma unroll
    for (int mt = 0; mt < 4; ++mt) {
      const int hh = strip + (mt << 4) + l15;
      const int c0 = (kt << 5) + (l4 << 3);
      short8 a;
#pragma unroll
      for (int j = 0; j < 8; ++j) a[j] = (short)tile[swz2(c0 + j, hh)];
      afr[kt][mt] = a;
    }
  // NO barrier: each wave's epilogue writes only its own h-strip; other
  // waves' A-fragments read only their own strips (disjoint).

  // ---- GEMM (4 passes of 16 rows to cap VGPR at 128) + fused epilogue ----
  // D[h,o'] = F[h,c]*Wc[c,o'], o'=p*64+o; B[k][n]: n=lane&15, k=8*(lane>>4)+j
#pragma unroll
  for (int mt = 0; mt < 4; ++mt) {
    f32x4 acc[8];
#pragma unroll
    for (int nt = 0; nt < 8; ++nt) {
      f32x4 z = {0.f, 0.f, 0.f, 0.f};
      acc[nt] = z;
    }
#pragma unroll
    for (int nt = 0; nt < 8; ++nt) {
      const int op = (nt << 4) + l15;
      const int p = op >> 6;
      const int o = op & 63;
      const unsigned short* wr0 = wb + (p << 12) + (o << 6) + (l4 << 3);
      const short8 b0 = *reinterpret_cast<const short8*>(wr0);
      const short8 b1 = *reinterpret_cast<const short8*>(wr0 + 32);
      acc[nt] = __builtin_amdgcn_mfma_f32_16x16x32_bf16(afr[0][mt], b0,
                                                        acc[nt], 0, 0, 0);
      acc[nt] = __builtin_amdgcn_mfma_f32_16x16x32_bf16(afr[1][mt], b1,
                                                        acc[nt], 0, 0, 0);
    }
    // epilogue rows: hh = strip + mt*16 + 4*(lane>>4) + reg
    float v0r[4], v1r[4], t0r[4], t1r[4];
#pragma unroll
    for (int r = 0; r < 4; ++r) {
      const int hh = strip + (mt << 4) + (l4 << 2) + r;
      const int off = (ip2ref(hh) << 8) + w;
      v0r[r] = vv[off];
      v1r[r] = vv[65536 + off];
      t0r[r] = tt[off];
      t1r[r] = tt[65536 + off];
    }
#pragma unroll
    for (int ntL = 0; ntL < 4; ++ntL) {
      const int o = (ntL << 4) + l15;
      const f32x4 lo = acc[ntL];
      const f32x4 hi = acc[ntL + 4];
#pragma unroll
      for (int r = 0; r < 4; ++r) {
        const float g0 = lo[r] * v0r[r];
        const float g1 = hi[r] * v1r[r];
        float rr = 0.f;
        const float q0 = fabsf(g0) - t0r[r];
        if (q0 > 0.f) rr += copysignf(q0, g0);
        const float q1 = fabsf(g1) - t1r[r];
        if (q1 > 0.f) rr += copysignf(q1, g1);
        const int hh = strip + (mt << 4) + (l4 << 2) + r;
        tile[swz2(o, hh)] = f2bf(rr);
      }
    }
  }
  __syncthreads();

  // ---- inverse Haar levels (8,7),(6,5),(4,3): scalar u16 quad lifting ----
#pragma unroll
  for (int ls = 8; ls >= 4; ls -= 2) {
    const int s = 1 << ls;
    const int hs = s >> 1;
    const int hq = hs >> 1;
    const int total = (256 >> ls) << 6;
    for (int idx = tid; idx < total; idx += 256) {
      const int c = idx & 63;
      const int q = idx >> 6;
      const int p0 = q * s;
      const float a = bf2f(tile[swz2(c, p0)]);
      const float d = bf2f(tile[swz2(c, p0 + hs)]);
      const float u0 = kNorm * (a + d), u1 = kNorm * (a - d);
      const float d0 = bf2f(tile[swz2(c, p0 + hq)]);
      const float d1 = bf2f(tile[swz2(c, p0 + hs + hq)]);
      tile[swz2(c, p0)]           = f2bf(kNorm * (u0 + d0));
      tile[swz2(c, p0 + hq)]      = f2bf(kNorm * (u0 - d0));
      tile[swz2(c, p0 + hs)]      = f2bf(kNorm * (u1 + d1));
      tile[swz2(c, p0 + hs + hq)] = f2bf(kNorm * (u1 - d1));
    }
    __syncthreads();
  }
  // ---- inverse levels (2,1): packed ----
#pragma unroll
  for (int it = 0; it < 16; ++it) {
    const int idx = tid + (it << 8);
    const int c = idx & 63;
    const int q = idx >> 6;
    const int p0 = q << 2;
    const unsigned dA = tile32[swz2(c, p0) >> 1];      // (a @ p0, d0 @ p0+1)
    const unsigned dB = tile32[swz2(c, p0 + 2) >> 1];  // (d @ p0+2, d1 @ p0+3)
    const float a = bf2f(dA), d0v = bf2f(dA >> 16);
    const float d = bf2f(dB), d1v = bf2f(dB >> 16);
    const float u0 = kNorm * (a + d), u1 = kNorm * (a - d);
    tile32[swz2(c, p0) >> 1]     = pk2(kNorm * (u0 + d0v), kNorm * (u0 - d0v));
    tile32[swz2(c, p0 + 2) >> 1] = pk2(kNorm * (u1 + d1v), kNorm * (u1 - d1v));
  }
  __syncthreads();

  // ---- slab store (mirror of load; block footprint private) ----
#pragma unroll
  for (int i = 0; i < 8; ++i) {
    const int c = cB + (i << 3);
    ushort8 raw;
#pragma unroll
    for (int j = 0; j < 4; ++j) {
      const unsigned dw = tile32[swz2(c, h0s + 2 * j) >> 1];
      raw[2 * j] = (unsigned short)(dw & 0xFFFFu);
      raw[2 * j + 1] = (unsigned short)(dw >> 16);
    }
    *reinterpret_cast<ushort8*>(base + ((size_t)c << 16) + h0s) = raw;
  }
}

// ---------------- Kernel 3: inverse Haar along W + residual add -------------
__global__ __launch_bounds__(256) void k_invW(const unsigned short* __restrict__ at,
                                              const float* __restrict__ x,
                                              float* __restrict__ y) {
  __shared__ float tile[256][33];  // 256 w (in-place order) x 32 h, pitch 33
  const int blk = blockIdx.x;      // img*8 + htile
  const int img = blk >> 3;
  const int h0 = (blk & 7) << 5;
  const int tid = threadIdx.x;
  const int g8 = tid >> 5;
  const int l = tid & 31;

  const unsigned short* __restrict__ base = at + ((size_t)img << 16) + h0;
#pragma unroll
  for (int k = 0; k < 32; ++k) {
    const int wr = (g8 << 5) + k;
    const int wp = ref2ip(wr);
    tile[wp][l] = bf2f(base[((size_t)wr << 8) + l]);
  }
  __syncthreads();

#pragma unroll
  for (int ls = 8; ls >= 1; --ls) {
    const int s = 1 << ls;
    const int hs = s >> 1;
    const int ppc = 256 >> ls;
    const int total = 32 * ppc;
    for (int idx = tid; idx < total; idx += 256) {
      const int hcq = idx & 31;
      const int i = idx >> 5;
      const int p0 = i * s;
      const float a = tile[p0][hcq];
      const float d = tile[p0 + hs][hcq];
      tile[p0][hcq] = kNorm * (a + d);
      tile[p0 + hs][hcq] = kNorm * (a - d);
    }
    __syncthreads();
  }

  const float* __restrict__ xs = x + ((size_t)img << 16) + ((size_t)h0 << 8);
  float* __restrict__ yd = y + ((size_t)img << 16) + ((size_t)h0 << 8);
#pragma unroll
  for (int j = 0; j < 32; ++j) {
    yd[(j << 8) + tid] = tile[tid][j] + xs[(j << 8) + tid];
  }
}

}  // namespace

extern "C" void kernel_launch(void* const* d_in, const int* in_sizes, int n_in,
                              void* d_out, int out_size, void* d_ws, size_t ws_size,
                              hipStream_t stream) {
  (void)in_sizes; (void)n_in; (void)out_size; (void)ws_size;
  const float* x  = (const float*)d_in[0];
  const float* vv = (const float*)d_in[1];
  const float* cw = (const float*)d_in[2];
  const float* tt = (const float*)d_in[3];
  float* y = (float*)d_out;
  unsigned short* ws = (unsigned short*)d_ws;           // 128 MiB bf16 slab
  unsigned short* wb = ws + ((size_t)64 << 20);         // bf16 weights (16 KiB)

  k_prep<<<32, 256, 0, stream>>>(cw, wb);
  k_fwdW<<<8192, 256, 0, stream>>>(x, ws);
  k_mid <<<4096, 256, 0, stream>>>(ws, vv, wb, tt);
  k_invW<<<8192, 256, 0, stream>>>(ws, x, y);
}

// Round 5
// 409.714 us; speedup vs baseline: 1.1363x; 1.1363x over previous
//
#include <hip/hip_runtime.h>
#include <hip/hip_bf16.h>

// Problem: B=16, C=64, H=256, W=256, P=2
// y = haar2d_inv( sum_p softthr( (haar2d(x)*v_p) @ w_p^T, tau_p ) ) + x
//
// ws layout: bf16 (b, c, w_ref, h) transposed buffer (128 MiB) + bf16 weights
//            (2x64x64) at element offset 64Mi.
//   k_prep : conv_w f32 -> bf16 (one-time, 16 KiB)
//   k_fwdW : x(f32) -> Hw(x), transposed+subband-permuted bf16 store to ws
//   k_mid  : per (b,w) slab: Hh fwd (bf16 LDS, packed L1+2) -> MFMA mix ->
//            Hh inv -> bf16 store in place. 32 KiB LDS.
//            __launch_bounds__(256,2): round-4's (256,4) forced VGPR=64 and
//            spilled (FETCH +174 MB scratch). 128 VGPR -> 4 blocks/CU anyway.
//   k_invW : ws -> Hw^{-1} + x -> y (f32, natural layout)

namespace {

constexpr float kNorm = 0.70710678118654752440f;

typedef __attribute__((ext_vector_type(8))) short short8;
typedef __attribute__((ext_vector_type(4))) float f32x4;
typedef __attribute__((ext_vector_type(8))) unsigned short ushort8;

// in-place lifting position -> reference subband position (n=256, 8 levels)
__device__ __forceinline__ int ip2ref(int p) {
  if (p == 0) return 0;
  const int j = __builtin_ctz(p) + 1;
  return (256 >> j) + (p >> j);
}
// reference subband position -> in-place lifting position
__device__ __forceinline__ int ref2ip(int r) {
  if (r == 0) return 0;
  const int tb = 31 - __builtin_clz(r);
  const int j = 8 - tb;
  return ((r - (1 << tb)) << j) | (1 << (j - 1));
}

__device__ __forceinline__ unsigned short f2bf(float f) {  // f32->bf16 RN
  unsigned int u = __float_as_uint(f);
  u += 0x7FFFu + ((u >> 16) & 1u);
  return (unsigned short)(u >> 16);
}
__device__ __forceinline__ float bf2f(unsigned int u) {
  return __uint_as_float((u & 0xFFFFu) << 16);
}
__device__ __forceinline__ unsigned pk2(float lo, float hi) {
  return (unsigned)f2bf(lo) | ((unsigned)f2bf(hi) << 16);
}

// ---------------- Kernel 0: conv_w f32 -> bf16 ------------------------------
__global__ __launch_bounds__(256) void k_prep(const float* __restrict__ cw,
                                              unsigned short* __restrict__ wb) {
  const int i = blockIdx.x * 256 + threadIdx.x;
  if (i < 8192) wb[i] = f2bf(cw[i]);
}

// ---------------- Kernel 1: forward Haar along W, transposed bf16 store -----
__global__ __launch_bounds__(256) void k_fwdW(const float* __restrict__ x,
                                              unsigned short* __restrict__ xt) {
  __shared__ float tile[32][257];  // 32 rows (h) x 256 cols (w), pitch 257
  const int blk = blockIdx.x;      // img*8 + htile
  const int img = blk >> 3;        // b*64 + c
  const int h0 = (blk & 7) << 5;
  const int tid = threadIdx.x;

  const float* __restrict__ src = x + ((size_t)img << 16) + ((size_t)h0 << 8);
#pragma unroll
  for (int j = 0; j < 32; ++j) tile[j][tid] = src[(j << 8) + tid];
  __syncthreads();

#pragma unroll
  for (int ls = 1; ls <= 8; ++ls) {
    const int s = 1 << ls;
    const int hs = s >> 1;
    const int ppr = 256 >> ls;
    const int total = 32 * ppr;
    for (int idx = tid; idx < total; idx += 256) {
      const int r = idx / ppr;
      const int i = idx - r * ppr;
      float* row = &tile[r][0];
      const int p0 = i * s;
      const float e = row[p0];
      const float o = row[p0 + hs];
      row[p0] = kNorm * (e + o);
      row[p0 + hs] = kNorm * (e - o);
    }
    __syncthreads();
  }

  // transposed bf16 write with in-place -> subband permutation: xt[img][wref][h]
  const int g8 = tid >> 5;
  const int l = tid & 31;
  unsigned short* __restrict__ dst = xt + ((size_t)img << 16) + h0;
#pragma unroll
  for (int k = 0; k < 32; ++k) {
    const int wp = g8 + (k << 3);
    const int wr = ip2ref(wp);
    dst[((size_t)wr << 8) + l] = f2bf(tile[l][wp]);
  }
}

// ---------------- Kernel 2: Hh fwd + MFMA mix + Hh inv (bf16 LDS) -----------
// LDS even-rotation swizzle: elem(c,h) = c*256 + ((h + 2c) & 255).
__device__ __forceinline__ int swz2(int c, int h) {
  return (c << 8) | ((h + 2 * c) & 255);
}

__global__ __launch_bounds__(256, 2) void k_mid(unsigned short* __restrict__ ws,
                                                const float* __restrict__ vv,
                                                const unsigned short* __restrict__ wb,
                                                const float* __restrict__ tt) {
  __shared__ unsigned short tile[16384];  // 32 KiB: 64 c x 256 h, swizzled
  unsigned int* tile32 = reinterpret_cast<unsigned int*>(tile);
  const int blk = blockIdx.x;  // b*256 + w
  const int b = blk >> 8;
  const int w = blk & 255;
  const int tid = threadIdx.x;

  unsigned short* __restrict__ base = ws + ((size_t)b << 22) + ((size_t)w << 8);

  // ---- slab load: c=(tid&7)+8i, h0=8*(tid>>3): 128B-coalesced global,
  //      conflict-free LDS ----
  const int cB = tid & 7;
  const int h0s = (tid >> 3) << 3;  // 0..248
#pragma unroll
  for (int i = 0; i < 8; ++i) {
    const int c = cB + (i << 3);
    const ushort8 raw =
        *reinterpret_cast<const ushort8*>(base + ((size_t)c << 16) + h0s);
#pragma unroll
    for (int j = 0; j < 4; ++j) {
      tile32[swz2(c, h0s + 2 * j) >> 1] =
          (unsigned)raw[2 * j] | ((unsigned)raw[2 * j + 1] << 16);
    }
  }
  __syncthreads();

  // ---- forward Haar along h: levels 1+2 packed (1 LDS op / 2 values) ----
#pragma unroll
  for (int it = 0; it < 16; ++it) {
    const int idx = tid + (it << 8);
    const int c = idx & 63;
    const int q = idx >> 6;
    const int p0 = q << 2;
    const unsigned dA = tile32[swz2(c, p0) >> 1];      // (e0,o0) @ p0,p0+1
    const unsigned dB = tile32[swz2(c, p0 + 2) >> 1];  // (e1,o1) @ p0+2,p0+3
    const float e0 = bf2f(dA), o0 = bf2f(dA >> 16);
    const float e1 = bf2f(dB), o1 = bf2f(dB >> 16);
    const float a0 = kNorm * (e0 + o0), dt0 = kNorm * (e0 - o0);
    const float a1 = kNorm * (e1 + o1), dt1 = kNorm * (e1 - o1);
    tile32[swz2(c, p0) >> 1]     = pk2(kNorm * (a0 + a1), dt0);
    tile32[swz2(c, p0 + 2) >> 1] = pk2(kNorm * (a0 - a1), dt1);
  }
  __syncthreads();

  // ---- forward Haar levels (3,4),(5,6),(7,8): scalar u16 quad lifting ----
#pragma unroll
  for (int ls = 3; ls <= 7; ls += 2) {
    const int s = 1 << ls;
    const int hs = s >> 1;
    const int s2 = s << 1;
    const int total = (128 >> ls) << 6;
    for (int idx = tid; idx < total; idx += 256) {
      const int c = idx & 63;
      const int q = idx >> 6;
      const int p0 = q * s2;
      const float e0 = bf2f(tile[swz2(c, p0)]);
      const float o0 = bf2f(tile[swz2(c, p0 + hs)]);
      const float e1 = bf2f(tile[swz2(c, p0 + s)]);
      const float o1 = bf2f(tile[swz2(c, p0 + s + hs)]);
      const float a0 = kNorm * (e0 + o0), dt0 = kNorm * (e0 - o0);
      const float a1 = kNorm * (e1 + o1), dt1 = kNorm * (e1 - o1);
      tile[swz2(c, p0)]          = f2bf(kNorm * (a0 + a1));
      tile[swz2(c, p0 + s)]      = f2bf(kNorm * (a0 - a1));
      tile[swz2(c, p0 + hs)]     = f2bf(dt0);
      tile[swz2(c, p0 + s + hs)] = f2bf(dt1);
    }
    __syncthreads();
  }

  // ---- A-fragment preload (bf16 already; no converts) ----
  // mfma_f32_16x16x32_bf16 A[m][k]: m=lane&15, k=8*(lane>>4)+j
  const int strip = (tid >> 6) << 6;  // wave id * 64 (h strip)
  const int l15 = tid & 15;
  const int l4 = (tid & 63) >> 4;
  short8 afr[2][4];
#pragma unroll
  for (int kt = 0; kt < 2; ++kt)
#pragma unroll
    for (int mt = 0; mt < 4; ++mt) {
      const int hh = strip + (mt << 4) + l15;
      const int c0 = (kt << 5) + (l4 << 3);
      short8 a;
#pragma unroll
      for (int j = 0; j < 8; ++j) a[j] = (short)tile[swz2(c0 + j, hh)];
      afr[kt][mt] = a;
    }
  // NO barrier: each wave's epilogue writes only its own h-strip; other
  // waves' A-fragments read only their own strips (disjoint).

  // ---- GEMM (4 passes of 16 rows) + fused epilogue ----
  // D[h,o'] = F[h,c]*Wc[c,o'], o'=p*64+o; B[k][n]: n=lane&15, k=8*(lane>>4)+j
#pragma unroll
  for (int mt = 0; mt < 4; ++mt) {
    f32x4 acc[8];
#pragma unroll
    for (int nt = 0; nt < 8; ++nt) {
      f32x4 z = {0.f, 0.f, 0.f, 0.f};
      acc[nt] = z;
    }
#pragma unroll
    for (int nt = 0; nt < 8; ++nt) {
      const int op = (nt << 4) + l15;
      const int p = op >> 6;
      const int o = op & 63;
      const unsigned short* wr0 = wb + (p << 12) + (o << 6) + (l4 << 3);
      const short8 b0 = *reinterpret_cast<const short8*>(wr0);
      const short8 b1 = *reinterpret_cast<const short8*>(wr0 + 32);
      acc[nt] = __builtin_amdgcn_mfma_f32_16x16x32_bf16(afr[0][mt], b0,
                                                        acc[nt], 0, 0, 0);
      acc[nt] = __builtin_amdgcn_mfma_f32_16x16x32_bf16(afr[1][mt], b1,
                                                        acc[nt], 0, 0, 0);
    }
    // epilogue rows: hh = strip + mt*16 + 4*(lane>>4) + reg
    float v0r[4], v1r[4], t0r[4], t1r[4];
#pragma unroll
    for (int r = 0; r < 4; ++r) {
      const int hh = strip + (mt << 4) + (l4 << 2) + r;
      const int off = (ip2ref(hh) << 8) + w;
      v0r[r] = vv[off];
      v1r[r] = vv[65536 + off];
      t0r[r] = tt[off];
      t1r[r] = tt[65536 + off];
    }
#pragma unroll
    for (int ntL = 0; ntL < 4; ++ntL) {
      const int o = (ntL << 4) + l15;
      const f32x4 lo = acc[ntL];
      const f32x4 hi = acc[ntL + 4];
#pragma unroll
      for (int r = 0; r < 4; ++r) {
        const float g0 = lo[r] * v0r[r];
        const float g1 = hi[r] * v1r[r];
        float rr = 0.f;
        const float q0 = fabsf(g0) - t0r[r];
        if (q0 > 0.f) rr += copysignf(q0, g0);
        const float q1 = fabsf(g1) - t1r[r];
        if (q1 > 0.f) rr += copysignf(q1, g1);
        const int hh = strip + (mt << 4) + (l4 << 2) + r;
        tile[swz2(o, hh)] = f2bf(rr);
      }
    }
  }
  __syncthreads();

  // ---- inverse Haar levels (8,7),(6,5),(4,3): scalar u16 quad lifting ----
#pragma unroll
  for (int ls = 8; ls >= 4; ls -= 2) {
    const int s = 1 << ls;
    const int hs = s >> 1;
    const int hq = hs >> 1;
    const int total = (256 >> ls) << 6;
    for (int idx = tid; idx < total; idx += 256) {
      const int c = idx & 63;
      const int q = idx >> 6;
      const int p0 = q * s;
      const float a = bf2f(tile[swz2(c, p0)]);
      const float d = bf2f(tile[swz2(c, p0 + hs)]);
      const float u0 = kNorm * (a + d), u1 = kNorm * (a - d);
      const float d0 = bf2f(tile[swz2(c, p0 + hq)]);
      const float d1 = bf2f(tile[swz2(c, p0 + hs + hq)]);
      tile[swz2(c, p0)]           = f2bf(kNorm * (u0 + d0));
      tile[swz2(c, p0 + hq)]      = f2bf(kNorm * (u0 - d0));
      tile[swz2(c, p0 + hs)]      = f2bf(kNorm * (u1 + d1));
      tile[swz2(c, p0 + hs + hq)] = f2bf(kNorm * (u1 - d1));
    }
    __syncthreads();
  }
  // ---- inverse levels (2,1): packed ----
#pragma unroll
  for (int it = 0; it < 16; ++it) {
    const int idx = tid + (it << 8);
    const int c = idx & 63;
    const int q = idx >> 6;
    const int p0 = q << 2;
    const unsigned dA = tile32[swz2(c, p0) >> 1];      // (a @ p0, d0 @ p0+1)
    const unsigned dB = tile32[swz2(c, p0 + 2) >> 1];  // (d @ p0+2, d1 @ p0+3)
    const float a = bf2f(dA), d0v = bf2f(dA >> 16);
    const float d = bf2f(dB), d1v = bf2f(dB >> 16);
    const float u0 = kNorm * (a + d), u1 = kNorm * (a - d);
    tile32[swz2(c, p0) >> 1]     = pk2(kNorm * (u0 + d0v), kNorm * (u0 - d0v));
    tile32[swz2(c, p0 + 2) >> 1] = pk2(kNorm * (u1 + d1v), kNorm * (u1 - d1v));
  }
  __syncthreads();

  // ---- slab store (mirror of load; block footprint private) ----
#pragma unroll
  for (int i = 0; i < 8; ++i) {
    const int c = cB + (i << 3);
    ushort8 raw;
#pragma unroll
    for (int j = 0; j < 4; ++j) {
      const unsigned dw = tile32[swz2(c, h0s + 2 * j) >> 1];
      raw[2 * j] = (unsigned short)(dw & 0xFFFFu);
      raw[2 * j + 1] = (unsigned short)(dw >> 16);
    }
    *reinterpret_cast<ushort8*>(base + ((size_t)c << 16) + h0s) = raw;
  }
}

// ---------------- Kernel 3: inverse Haar along W + residual add -------------
__global__ __launch_bounds__(256) void k_invW(const unsigned short* __restrict__ at,
                                              const float* __restrict__ x,
                                              float* __restrict__ y) {
  __shared__ float tile[256][33];  // 256 w (in-place order) x 32 h, pitch 33
  const int blk = blockIdx.x;      // img*8 + htile
  const int img = blk >> 3;
  const int h0 = (blk & 7) << 5;
  const int tid = threadIdx.x;
  const int g8 = tid >> 5;
  const int l = tid & 31;

  const unsigned short* __restrict__ base = at + ((size_t)img << 16) + h0;
#pragma unroll
  for (int k = 0; k < 32; ++k) {
    const int wr = (g8 << 5) + k;
    const int wp = ref2ip(wr);
    tile[wp][l] = bf2f(base[((size_t)wr << 8) + l]);
  }
  __syncthreads();

#pragma unroll
  for (int ls = 8; ls >= 1; --ls) {
    const int s = 1 << ls;
    const int hs = s >> 1;
    const int ppc = 256 >> ls;
    const int total = 32 * ppc;
    for (int idx = tid; idx < total; idx += 256) {
      const int hcq = idx & 31;
      const int i = idx >> 5;
      const int p0 = i * s;
      const float a = tile[p0][hcq];
      const float d = tile[p0 + hs][hcq];
      tile[p0][hcq] = kNorm * (a + d);
      tile[p0 + hs][hcq] = kNorm * (a - d);
    }
    __syncthreads();
  }

  const float* __restrict__ xs = x + ((size_t)img << 16) + ((size_t)h0 << 8);
  float* __restrict__ yd = y + ((size_t)img << 16) + ((size_t)h0 << 8);
#pragma unroll
  for (int j = 0; j < 32; ++j) {
    yd[(j << 8) + tid] = tile[tid][j] + xs[(j << 8) + tid];
  }
}

}  // namespace

extern "C" void kernel_launch(void* const* d_in, const int* in_sizes, int n_in,
                              void* d_out, int out_size, void* d_ws, size_t ws_size,
                              hipStream_t stream) {
  (void)in_sizes; (void)n_in; (void)out_size; (void)ws_size;
  const float* x  = (const float*)d_in[0];
  const float* vv = (const float*)d_in[1];
  const float* cw = (const float*)d_in[2];
  const float* tt = (const float*)d_in[3];
  float* y = (float*)d_out;
  unsigned short* ws = (unsigned short*)d_ws;           // 128 MiB bf16 slab
  unsigned short* wb = ws + ((size_t)64 << 20);         // bf16 weights (16 KiB)

  k_prep<<<32, 256, 0, stream>>>(cw, wb);
  k_fwdW<<<8192, 256, 0, stream>>>(x, ws);
  k_mid <<<4096, 256, 0, stream>>>(ws, vv, wb, tt);
  k_invW<<<8192, 256, 0, stream>>>(ws, x, y);
}

// Round 6
// 349.720 us; speedup vs baseline: 1.3312x; 1.1715x over previous
//
#include <hip/hip_runtime.h>
#include <hip/hip_bf16.h>

// Problem: B=16, C=64, H=256, W=256, P=2
// y = haar2d_inv( sum_p softthr( (haar2d(x)*v_p) @ w_p^T, tau_p ) ) + x
//
// ws: bf16 (b,c,wref,h) slab (128 MiB) + bf16 weights + packed/permuted v,tau.
//   k_prep : conv_w->bf16; v,tau -> bf16x2 packed, [w][h_inplace] layout
//   k_fwdW : x(f32) -> Hw(x), transposed+subband-permuted bf16 store to ws
//   k_mid  : per (b,w) slab: staged-lifting Haar-H fwd (levels 1-3 in reg,
//            4-6 in reg via stride-8, 7-8 one wave) -> MFMA mix -> staged
//            inverse -> store. h-major packed LDS tile, 6 barriers.
//   k_invW : ws -> Hw^{-1} + x -> y (f32, natural layout)

namespace {

constexpr float kNorm = 0.70710678118654752440f;

typedef __attribute__((ext_vector_type(8))) short short8;
typedef __attribute__((ext_vector_type(4))) float f32x4;
typedef __attribute__((ext_vector_type(8))) unsigned short ushort8;
typedef __attribute__((ext_vector_type(4))) unsigned int uint4v;

// in-place lifting position -> reference subband position (n=256, 8 levels)
__device__ __forceinline__ int ip2ref(int p) {
  if (p == 0) return 0;
  const int j = __builtin_ctz(p) + 1;
  return (256 >> j) + (p >> j);
}
// reference subband position -> in-place lifting position
__device__ __forceinline__ int ref2ip(int r) {
  if (r == 0) return 0;
  const int tb = 31 - __builtin_clz(r);
  const int j = 8 - tb;
  return ((r - (1 << tb)) << j) | (1 << (j - 1));
}

__device__ __forceinline__ unsigned short f2bf(float f) {  // f32->bf16 RN
  unsigned int u = __float_as_uint(f);
  u += 0x7FFFu + ((u >> 16) & 1u);
  return (unsigned short)(u >> 16);
}
__device__ __forceinline__ float bf2f(unsigned int u) {
  return __uint_as_float((u & 0xFFFFu) << 16);
}
__device__ __forceinline__ unsigned pk2(float lo, float hi) {
  return (unsigned)f2bf(lo) | ((unsigned)f2bf(hi) << 16);
}

// 3-level forward Haar lifting on 8 values (in-place position convention)
__device__ __forceinline__ void lift3f(const float f[8], float o[8]) {
  const float a0 = kNorm * (f[0] + f[1]), d10 = kNorm * (f[0] - f[1]);
  const float a1 = kNorm * (f[2] + f[3]), d11 = kNorm * (f[2] - f[3]);
  const float a2 = kNorm * (f[4] + f[5]), d12 = kNorm * (f[4] - f[5]);
  const float a3 = kNorm * (f[6] + f[7]), d13 = kNorm * (f[6] - f[7]);
  const float b0 = kNorm * (a0 + a1), d20 = kNorm * (a0 - a1);
  const float b1 = kNorm * (a2 + a3), d21 = kNorm * (a2 - a3);
  o[0] = kNorm * (b0 + b1);
  o[4] = kNorm * (b0 - b1);
  o[2] = d20; o[6] = d21;
  o[1] = d10; o[3] = d11; o[5] = d12; o[7] = d13;
}
// inverse of lift3f
__device__ __forceinline__ void ilift3f(const float f[8], float o[8]) {
  const float b0 = kNorm * (f[0] + f[4]), b1 = kNorm * (f[0] - f[4]);
  const float a0 = kNorm * (b0 + f[2]), a1 = kNorm * (b0 - f[2]);
  const float a2 = kNorm * (b1 + f[6]), a3 = kNorm * (b1 - f[6]);
  o[0] = kNorm * (a0 + f[1]); o[1] = kNorm * (a0 - f[1]);
  o[2] = kNorm * (a1 + f[3]); o[3] = kNorm * (a1 - f[3]);
  o[4] = kNorm * (a2 + f[5]); o[5] = kNorm * (a2 - f[5]);
  o[6] = kNorm * (a3 + f[7]); o[7] = kNorm * (a3 - f[7]);
}

// ---------------- Kernel 0: weights -> bf16; v,tau -> packed/permuted -------
__global__ __launch_bounds__(256) void k_prep(const float* __restrict__ cw,
                                              const float* __restrict__ vv,
                                              const float* __restrict__ tt,
                                              unsigned short* __restrict__ wb,
                                              unsigned int* __restrict__ vpk,
                                              unsigned int* __restrict__ tpk) {
  const int idx = blockIdx.x * 256 + threadIdx.x;  // 65536 = 256 w x 256 hp
  if (idx < 8192) wb[idx] = f2bf(cw[idx]);
  const int w = idx >> 8;
  const int hp = idx & 255;                 // in-place h position
  const int off = (ip2ref(hp) << 8) + w;    // reference coord
  vpk[idx] = pk2(vv[off], vv[65536 + off]);
  tpk[idx] = pk2(tt[off], tt[65536 + off]);
}

// ---------------- Kernel 1: forward Haar along W, transposed bf16 store -----
__global__ __launch_bounds__(256) void k_fwdW(const float* __restrict__ x,
                                              unsigned short* __restrict__ xt) {
  __shared__ float tile[32][257];  // 32 rows (h) x 256 cols (w), pitch 257
  const int blk = blockIdx.x;      // img*8 + htile
  const int img = blk >> 3;        // b*64 + c
  const int h0 = (blk & 7) << 5;
  const int tid = threadIdx.x;

  const float* __restrict__ src = x + ((size_t)img << 16) + ((size_t)h0 << 8);
#pragma unroll
  for (int j = 0; j < 32; ++j) tile[j][tid] = src[(j << 8) + tid];
  __syncthreads();

#pragma unroll
  for (int ls = 1; ls <= 8; ++ls) {
    const int s = 1 << ls;
    const int hs = s >> 1;
    const int ppr = 256 >> ls;
    const int total = 32 * ppr;
    for (int idx = tid; idx < total; idx += 256) {
      const int r = idx / ppr;
      const int i = idx - r * ppr;
      float* row = &tile[r][0];
      const int p0 = i * s;
      const float e = row[p0];
      const float o = row[p0 + hs];
      row[p0] = kNorm * (e + o);
      row[p0 + hs] = kNorm * (e - o);
    }
    __syncthreads();
  }

  // transposed bf16 write with in-place -> subband permutation: xt[img][wref][h]
  const int g8 = tid >> 5;
  const int l = tid & 31;
  unsigned short* __restrict__ dst = xt + ((size_t)img << 16) + h0;
#pragma unroll
  for (int k = 0; k < 32; ++k) {
    const int wp = g8 + (k << 3);
    const int wr = ip2ref(wp);
    dst[((size_t)wr << 8) + l] = f2bf(tile[l][wp]);
  }
}

// ---------------- Kernel 2: staged Haar-H + MFMA mix (h-major packed LDS) ---
// tile dword (h, cdw): dwidx = h*32 + ((cdw + 4*(h&7) + 8*((h>>3)&3)) & 31)
// Rotation keeps 4-dword alignment (b128-able) and makes every phase <=2-way.
__device__ __forceinline__ int swzc(int h, int cdw) {
  return (h << 5) | ((cdw + ((h & 7) << 2) + (((h >> 3) & 3) << 3)) & 31);
}

__global__ __launch_bounds__(256, 4) void k_mid(
    unsigned short* __restrict__ ws, const unsigned short* __restrict__ wb,
    const unsigned int* __restrict__ vpk, const unsigned int* __restrict__ tpk) {
  __shared__ unsigned int t32[8192];  // 32 KiB: [h=256][cdw=32] swizzled
  __shared__ unsigned int vt[512];    // [0..255]=v packed, [256..511]=tau packed
  unsigned short* t16 = reinterpret_cast<unsigned short*>(t32);

  const int blk = blockIdx.x;  // b*256 + w
  const int b = blk >> 8;
  const int w = blk & 255;
  const int tid = threadIdx.x;

  unsigned short* __restrict__ base = ws + ((size_t)b << 22) + ((size_t)w << 8);

  // stage v/tau (coalesced; already ip2ref-permuted by k_prep)
  vt[tid] = vpk[(w << 8) + tid];
  vt[256 + tid] = tpk[(w << 8) + tid];

  // ---- S1: global->reg, fwd levels 1-3 in registers, write tile ----
  const int cdw = tid >> 3;  // 0..31 (channel pair)
  const int c0 = cdw << 1;
  const int o8 = tid & 7;
  ushort8 rA[4], rB[4];
#pragma unroll
  for (int it = 0; it < 4; ++it) {
    const int h0 = (o8 << 3) + (it << 6);
    rA[it] = *reinterpret_cast<const ushort8*>(base + ((size_t)c0 << 16) + h0);
    rB[it] =
        *reinterpret_cast<const ushort8*>(base + ((size_t)(c0 + 1) << 16) + h0);
  }
#pragma unroll
  for (int it = 0; it < 4; ++it) {
    const int h0 = (o8 << 3) + (it << 6);
    float fa[8], fb[8], oa[8], ob[8];
#pragma unroll
    for (int j = 0; j < 8; ++j) {
      fa[j] = bf2f(rA[it][j]);
      fb[j] = bf2f(rB[it][j]);
    }
    lift3f(fa, oa);
    lift3f(fb, ob);
#pragma unroll
    for (int j = 0; j < 8; ++j) t32[swzc(h0 + j, cdw)] = pk2(oa[j], ob[j]);
  }
  __syncthreads();

  // ---- S2: fwd levels 4-6 (8 values @ stride 8), 128 threads ----
  if (tid < 128) {
    const int cd = tid & 31;
    const int h0 = (tid >> 5) << 6;
    unsigned int g[8];
#pragma unroll
    for (int k = 0; k < 8; ++k) g[k] = t32[swzc(h0 + (k << 3), cd)];
    float fa[8], fb[8], oa[8], ob[8];
#pragma unroll
    for (int k = 0; k < 8; ++k) {
      fa[k] = bf2f(g[k]);
      fb[k] = bf2f(g[k] >> 16);
    }
    lift3f(fa, oa);
    lift3f(fb, ob);
#pragma unroll
    for (int k = 0; k < 8; ++k)
      t32[swzc(h0 + (k << 3), cd)] = pk2(oa[k], ob[k]);
  }
  __syncthreads();

  // ---- S3: fwd levels 7-8 (4 values @ stride 64), 32 threads ----
  if (tid < 32) {
    unsigned int g[4];
#pragma unroll
    for (int k = 0; k < 4; ++k) g[k] = t32[swzc(k << 6, tid)];
    float fa[4], fb[4];
#pragma unroll
    for (int k = 0; k < 4; ++k) {
      fa[k] = bf2f(g[k]);
      fb[k] = bf2f(g[k] >> 16);
    }
    const float aa0 = kNorm * (fa[0] + fa[1]), da0 = kNorm * (fa[0] - fa[1]);
    const float aa1 = kNorm * (fa[2] + fa[3]), da1 = kNorm * (fa[2] - fa[3]);
    const float ab0 = kNorm * (fb[0] + fb[1]), db0 = kNorm * (fb[0] - fb[1]);
    const float ab1 = kNorm * (fb[2] + fb[3]), db1 = kNorm * (fb[2] - fb[3]);
    t32[swzc(0, tid)] = pk2(kNorm * (aa0 + aa1), kNorm * (ab0 + ab1));
    t32[swzc(64, tid)] = pk2(da0, db0);
    t32[swzc(128, tid)] = pk2(kNorm * (aa0 - aa1), kNorm * (ab0 - ab1));
    t32[swzc(192, tid)] = pk2(da1, db1);
  }
  __syncthreads();

  // ---- GEMM + fused epilogue, per-wave 64-row strip, per-mt A reload ----
  // mfma_f32_16x16x32_bf16: A[m][k]: m=lane&15, k=8*(lane>>4)+j (k=c)
  // D: col o'=lane&15, row = strip+16mt+4*(lane>>4)+reg
  const int strip = (tid >> 6) << 6;
  const int l15 = tid & 15;
  const int l4 = (tid & 63) >> 4;
#pragma unroll 1
  for (int mt = 0; mt < 4; ++mt) {
    const int hh = strip + (mt << 4) + l15;
    const short8 a0 =
        *reinterpret_cast<const short8*>(&t32[swzc(hh, l4 << 2)]);
    const short8 a1 =
        *reinterpret_cast<const short8*>(&t32[swzc(hh, 16 + (l4 << 2))]);
    f32x4 acc[8];
#pragma unroll
    for (int nt = 0; nt < 8; ++nt) {
      f32x4 z = {0.f, 0.f, 0.f, 0.f};
      acc[nt] = z;
    }
#pragma unroll
    for (int nt = 0; nt < 8; ++nt) {
      const int op = (nt << 4) + l15;  // o' in [0,128)
      const int p = op >> 6;
      const int o = op & 63;
      const unsigned short* wr0 = wb + (p << 12) + (o << 6) + (l4 << 3);
      const short8 b0 = *reinterpret_cast<const short8*>(wr0);
      const short8 b1 = *reinterpret_cast<const short8*>(wr0 + 32);
      acc[nt] = __builtin_amdgcn_mfma_f32_16x16x32_bf16(a0, b0, acc[nt], 0, 0, 0);
      acc[nt] = __builtin_amdgcn_mfma_f32_16x16x32_bf16(a1, b1, acc[nt], 0, 0, 0);
    }
    const int hb = strip + (mt << 4) + (l4 << 2);
    const uint4v vq = *reinterpret_cast<const uint4v*>(&vt[hb]);
    const uint4v tq = *reinterpret_cast<const uint4v*>(&vt[256 + hb]);
#pragma unroll
    for (int ntL = 0; ntL < 4; ++ntL) {
      const int o = (ntL << 4) + l15;
      const f32x4 lo = acc[ntL];
      const f32x4 hi = acc[ntL + 4];
#pragma unroll
      for (int r = 0; r < 4; ++r) {
        const float v0 = bf2f(vq[r]), v1 = bf2f(vq[r] >> 16);
        const float t0 = bf2f(tq[r]), t1 = bf2f(tq[r] >> 16);
        const float g0 = lo[r] * v0;
        const float g1 = hi[r] * v1;
        float rr = 0.f;
        const float q0 = fabsf(g0) - t0;
        if (q0 > 0.f) rr += copysignf(q0, g0);
        const float q1 = fabsf(g1) - t1;
        if (q1 > 0.f) rr += copysignf(q1, g1);
        t16[(swzc(hb + r, o >> 1) << 1) | (o & 1)] = f2bf(rr);
      }
    }
  }
  __syncthreads();

  // ---- inverse S3: levels 8,7 ----
  if (tid < 32) {
    unsigned int g[4];
#pragma unroll
    for (int k = 0; k < 4; ++k) g[k] = t32[swzc(k << 6, tid)];
    float fa[4], fb[4];
#pragma unroll
    for (int k = 0; k < 4; ++k) {
      fa[k] = bf2f(g[k]);
      fb[k] = bf2f(g[k] >> 16);
    }
    const float ua0 = kNorm * (fa[0] + fa[2]), ua1 = kNorm * (fa[0] - fa[2]);
    const float ub0 = kNorm * (fb[0] + fb[2]), ub1 = kNorm * (fb[0] - fb[2]);
    t32[swzc(0, tid)] = pk2(kNorm * (ua0 + fa[1]), kNorm * (ub0 + fb[1]));
    t32[swzc(64, tid)] = pk2(kNorm * (ua0 - fa[1]), kNorm * (ub0 - fb[1]));
    t32[swzc(128, tid)] = pk2(kNorm * (ua1 + fa[3]), kNorm * (ub1 + fb[3]));
    t32[swzc(192, tid)] = pk2(kNorm * (ua1 - fa[3]), kNorm * (ub1 - fb[3]));
  }
  __syncthreads();

  // ---- inverse S2: levels 6,5,4 ----
  if (tid < 128) {
    const int cd = tid & 31;
    const int h0 = (tid >> 5) << 6;
    unsigned int g[8];
#pragma unroll
    for (int k = 0; k < 8; ++k) g[k] = t32[swzc(h0 + (k << 3), cd)];
    float fa[8], fb[8], oa[8], ob[8];
#pragma unroll
    for (int k = 0; k < 8; ++k) {
      fa[k] = bf2f(g[k]);
      fb[k] = bf2f(g[k] >> 16);
    }
    ilift3f(fa, oa);
    ilift3f(fb, ob);
#pragma unroll
    for (int k = 0; k < 8; ++k)
      t32[swzc(h0 + (k << 3), cd)] = pk2(oa[k], ob[k]);
  }
  __syncthreads();

  // ---- inverse S1: levels 3,2,1 in registers + global store ----
#pragma unroll
  for (int it = 0; it < 4; ++it) {
    const int h0 = (o8 << 3) + (it << 6);
    unsigned int g[8];
#pragma unroll
    for (int j = 0; j < 8; ++j) g[j] = t32[swzc(h0 + j, cdw)];
    float fa[8], fb[8], oa[8], ob[8];
#pragma unroll
    for (int j = 0; j < 8; ++j) {
      fa[j] = bf2f(g[j]);
      fb[j] = bf2f(g[j] >> 16);
    }
    ilift3f(fa, oa);
    ilift3f(fb, ob);
    ushort8 sA, sB;
#pragma unroll
    for (int j = 0; j < 8; ++j) {
      sA[j] = f2bf(oa[j]);
      sB[j] = f2bf(ob[j]);
    }
    *reinterpret_cast<ushort8*>(base + ((size_t)c0 << 16) + h0) = sA;
    *reinterpret_cast<ushort8*>(base + ((size_t)(c0 + 1) << 16) + h0) = sB;
  }
}

// ---------------- Kernel 3: inverse Haar along W + residual add -------------
__global__ __launch_bounds__(256) void k_invW(const unsigned short* __restrict__ at,
                                              const float* __restrict__ x,
                                              float* __restrict__ y) {
  __shared__ float tile[256][33];  // 256 w (in-place order) x 32 h, pitch 33
  const int blk = blockIdx.x;      // img*8 + htile
  const int img = blk >> 3;
  const int h0 = (blk & 7) << 5;
  const int tid = threadIdx.x;
  const int g8 = tid >> 5;
  const int l = tid & 31;

  const unsigned short* __restrict__ base = at + ((size_t)img << 16) + h0;
#pragma unroll
  for (int k = 0; k < 32; ++k) {
    const int wr = (g8 << 5) + k;
    const int wp = ref2ip(wr);
    tile[wp][l] = bf2f(base[((size_t)wr << 8) + l]);
  }
  __syncthreads();

#pragma unroll
  for (int ls = 8; ls >= 1; --ls) {
    const int s = 1 << ls;
    const int hs = s >> 1;
    const int ppc = 256 >> ls;
    const int total = 32 * ppc;
    for (int idx = tid; idx < total; idx += 256) {
      const int hcq = idx & 31;
      const int i = idx >> 5;
      const int p0 = i * s;
      const float a = tile[p0][hcq];
      const float d = tile[p0 + hs][hcq];
      tile[p0][hcq] = kNorm * (a + d);
      tile[p0 + hs][hcq] = kNorm * (a - d);
    }
    __syncthreads();
  }

  const float* __restrict__ xs = x + ((size_t)img << 16) + ((size_t)h0 << 8);
  float* __restrict__ yd = y + ((size_t)img << 16) + ((size_t)h0 << 8);
#pragma unroll
  for (int j = 0; j < 32; ++j) {
    yd[(j << 8) + tid] = tile[tid][j] + xs[(j << 8) + tid];
  }
}

}  // namespace

extern "C" void kernel_launch(void* const* d_in, const int* in_sizes, int n_in,
                              void* d_out, int out_size, void* d_ws, size_t ws_size,
                              hipStream_t stream) {
  (void)in_sizes; (void)n_in; (void)out_size; (void)ws_size;
  const float* x  = (const float*)d_in[0];
  const float* vv = (const float*)d_in[1];
  const float* cw = (const float*)d_in[2];
  const float* tt = (const float*)d_in[3];
  float* y = (float*)d_out;
  unsigned short* ws = (unsigned short*)d_ws;      // 128 MiB bf16 slab
  unsigned short* wb = ws + ((size_t)64 << 20);    // bf16 weights (16 KiB)
  unsigned int* vpk = (unsigned int*)(ws + ((size_t)64 << 20) + 16384);
  unsigned int* tpk = vpk + 65536;                 // 256 KiB each

  k_prep<<<256, 256, 0, stream>>>(cw, vv, tt, wb, vpk, tpk);
  k_fwdW<<<8192, 256, 0, stream>>>(x, ws);
  k_mid <<<4096, 256, 0, stream>>>(ws, wb, vpk, tpk);
  k_invW<<<8192, 256, 0, stream>>>(ws, x, y);
}

// Round 7
// 344.754 us; speedup vs baseline: 1.3504x; 1.0144x over previous
//
#include <hip/hip_runtime.h>
#include <hip/hip_bf16.h>

// Problem: B=16, C=64, H=256, W=256, P=2
// y = haar2d_inv( sum_p softthr( (haar2d(x)*v_p) @ w_p^T, tau_p ) ) + x
//
// ws: bf16 (b,c,wref,h) slab (128 MiB) + bf16 weights + packed/permuted v,tau.
//   k_prep : conv_w->bf16; v,tau -> bf16x2 packed, [w][h_inplace] layout
//   k_fwdW : x(f32) -> Hw(x), transposed+subband-permuted bf16 store to ws
//   k_mid  : per (b,w) slab: staged-lifting Haar-H fwd (levels 1-3 in reg,
//            4-6 in reg via stride-8, 7-8 one wave) -> MFMA mix -> staged
//            inverse -> store. h-major packed LDS tile, 6 barriers.
//            GEMM restructured into per-o-group 8-reg accumulators so the
//            unified VGPR+AGPR live set fits 128 (launch_bounds(256,4)
//            previously spilled ~200 MB scratch: round-6 WRITE_SIZE 335 MB).
//   k_invW : ws -> Hw^{-1} + x -> y (f32, natural layout)

namespace {

constexpr float kNorm = 0.70710678118654752440f;

typedef __attribute__((ext_vector_type(8))) short short8;
typedef __attribute__((ext_vector_type(4))) float f32x4;
typedef __attribute__((ext_vector_type(8))) unsigned short ushort8;
typedef __attribute__((ext_vector_type(4))) unsigned int uint4v;

// in-place lifting position -> reference subband position (n=256, 8 levels)
__device__ __forceinline__ int ip2ref(int p) {
  if (p == 0) return 0;
  const int j = __builtin_ctz(p) + 1;
  return (256 >> j) + (p >> j);
}
// reference subband position -> in-place lifting position
__device__ __forceinline__ int ref2ip(int r) {
  if (r == 0) return 0;
  const int tb = 31 - __builtin_clz(r);
  const int j = 8 - tb;
  return ((r - (1 << tb)) << j) | (1 << (j - 1));
}

__device__ __forceinline__ unsigned short f2bf(float f) {  // f32->bf16 RN
  unsigned int u = __float_as_uint(f);
  u += 0x7FFFu + ((u >> 16) & 1u);
  return (unsigned short)(u >> 16);
}
__device__ __forceinline__ float bf2f(unsigned int u) {
  return __uint_as_float((u & 0xFFFFu) << 16);
}
__device__ __forceinline__ unsigned pk2(float lo, float hi) {
  return (unsigned)f2bf(lo) | ((unsigned)f2bf(hi) << 16);
}

// 3-level forward Haar lifting on 8 values (in-place position convention)
__device__ __forceinline__ void lift3f(const float f[8], float o[8]) {
  const float a0 = kNorm * (f[0] + f[1]), d10 = kNorm * (f[0] - f[1]);
  const float a1 = kNorm * (f[2] + f[3]), d11 = kNorm * (f[2] - f[3]);
  const float a2 = kNorm * (f[4] + f[5]), d12 = kNorm * (f[4] - f[5]);
  const float a3 = kNorm * (f[6] + f[7]), d13 = kNorm * (f[6] - f[7]);
  const float b0 = kNorm * (a0 + a1), d20 = kNorm * (a0 - a1);
  const float b1 = kNorm * (a2 + a3), d21 = kNorm * (a2 - a3);
  o[0] = kNorm * (b0 + b1);
  o[4] = kNorm * (b0 - b1);
  o[2] = d20; o[6] = d21;
  o[1] = d10; o[3] = d11; o[5] = d12; o[7] = d13;
}
// inverse of lift3f
__device__ __forceinline__ void ilift3f(const float f[8], float o[8]) {
  const float b0 = kNorm * (f[0] + f[4]), b1 = kNorm * (f[0] - f[4]);
  const float a0 = kNorm * (b0 + f[2]), a1 = kNorm * (b0 - f[2]);
  const float a2 = kNorm * (b1 + f[6]), a3 = kNorm * (b1 - f[6]);
  o[0] = kNorm * (a0 + f[1]); o[1] = kNorm * (a0 - f[1]);
  o[2] = kNorm * (a1 + f[3]); o[3] = kNorm * (a1 - f[3]);
  o[4] = kNorm * (a2 + f[5]); o[5] = kNorm * (a2 - f[5]);
  o[6] = kNorm * (a3 + f[7]); o[7] = kNorm * (a3 - f[7]);
}

// ---------------- Kernel 0: weights -> bf16; v,tau -> packed/permuted -------
__global__ __launch_bounds__(256) void k_prep(const float* __restrict__ cw,
                                              const float* __restrict__ vv,
                                              const float* __restrict__ tt,
                                              unsigned short* __restrict__ wb,
                                              unsigned int* __restrict__ vpk,
                                              unsigned int* __restrict__ tpk) {
  const int idx = blockIdx.x * 256 + threadIdx.x;  // 65536 = 256 w x 256 hp
  if (idx < 8192) wb[idx] = f2bf(cw[idx]);
  const int w = idx >> 8;
  const int hp = idx & 255;                 // in-place h position
  const int off = (ip2ref(hp) << 8) + w;    // reference coord
  vpk[idx] = pk2(vv[off], vv[65536 + off]);
  tpk[idx] = pk2(tt[off], tt[65536 + off]);
}

// ---------------- Kernel 1: forward Haar along W, transposed bf16 store -----
__global__ __launch_bounds__(256) void k_fwdW(const float* __restrict__ x,
                                              unsigned short* __restrict__ xt) {
  __shared__ float tile[32][257];  // 32 rows (h) x 256 cols (w), pitch 257
  const int blk = blockIdx.x;      // img*8 + htile
  const int img = blk >> 3;        // b*64 + c
  const int h0 = (blk & 7) << 5;
  const int tid = threadIdx.x;

  const float* __restrict__ src = x + ((size_t)img << 16) + ((size_t)h0 << 8);
#pragma unroll
  for (int j = 0; j < 32; ++j) tile[j][tid] = src[(j << 8) + tid];
  __syncthreads();

#pragma unroll
  for (int ls = 1; ls <= 8; ++ls) {
    const int s = 1 << ls;
    const int hs = s >> 1;
    const int ppr = 256 >> ls;
    const int total = 32 * ppr;
    for (int idx = tid; idx < total; idx += 256) {
      const int r = idx / ppr;
      const int i = idx - r * ppr;
      float* row = &tile[r][0];
      const int p0 = i * s;
      const float e = row[p0];
      const float o = row[p0 + hs];
      row[p0] = kNorm * (e + o);
      row[p0 + hs] = kNorm * (e - o);
    }
    __syncthreads();
  }

  // transposed bf16 write with in-place -> subband permutation: xt[img][wref][h]
  const int g8 = tid >> 5;
  const int l = tid & 31;
  unsigned short* __restrict__ dst = xt + ((size_t)img << 16) + h0;
#pragma unroll
  for (int k = 0; k < 32; ++k) {
    const int wp = g8 + (k << 3);
    const int wr = ip2ref(wp);
    dst[((size_t)wr << 8) + l] = f2bf(tile[l][wp]);
  }
}

// ---------------- Kernel 2: staged Haar-H + MFMA mix (h-major packed LDS) ---
// tile dword (h, cdw): dwidx = h*32 + ((cdw + 4*(h&7) + 8*((h>>3)&3)) & 31)
// Rotation keeps 4-dword alignment (b128-able) and makes every phase <=2-way.
__device__ __forceinline__ int swzc(int h, int cdw) {
  return (h << 5) | ((cdw + ((h & 7) << 2) + (((h >> 3) & 3) << 3)) & 31);
}

__global__ __launch_bounds__(256, 4) void k_mid(
    unsigned short* __restrict__ ws, const unsigned short* __restrict__ wb,
    const unsigned int* __restrict__ vpk, const unsigned int* __restrict__ tpk) {
  __shared__ unsigned int t32[8192];  // 32 KiB: [h=256][cdw=32] swizzled
  __shared__ unsigned int vt[512];    // [0..255]=v packed, [256..511]=tau packed
  unsigned short* t16 = reinterpret_cast<unsigned short*>(t32);

  const int blk = blockIdx.x;  // b*256 + w
  const int b = blk >> 8;
  const int w = blk & 255;
  const int tid = threadIdx.x;

  unsigned short* __restrict__ base = ws + ((size_t)b << 22) + ((size_t)w << 8);

  // stage v/tau (coalesced; already ip2ref-permuted by k_prep)
  vt[tid] = vpk[(w << 8) + tid];
  vt[256 + tid] = tpk[(w << 8) + tid];

  // ---- S1: global->reg, fwd levels 1-3 in registers, write tile ----
  const int cdw = tid >> 3;  // 0..31 (channel pair)
  const int c0 = cdw << 1;
  const int o8 = tid & 7;
#pragma unroll
  for (int it = 0; it < 4; ++it) {
    const int h0 = (o8 << 3) + (it << 6);
    const ushort8 rA =
        *reinterpret_cast<const ushort8*>(base + ((size_t)c0 << 16) + h0);
    const ushort8 rB =
        *reinterpret_cast<const ushort8*>(base + ((size_t)(c0 + 1) << 16) + h0);
    float fa[8], fb[8], oa[8], ob[8];
#pragma unroll
    for (int j = 0; j < 8; ++j) {
      fa[j] = bf2f(rA[j]);
      fb[j] = bf2f(rB[j]);
    }
    lift3f(fa, oa);
    lift3f(fb, ob);
#pragma unroll
    for (int j = 0; j < 8; ++j) t32[swzc(h0 + j, cdw)] = pk2(oa[j], ob[j]);
  }
  __syncthreads();

  // ---- S2: fwd levels 4-6 (8 values @ stride 8), 128 threads ----
  if (tid < 128) {
    const int cd = tid & 31;
    const int h0 = (tid >> 5) << 6;
    unsigned int g[8];
#pragma unroll
    for (int k = 0; k < 8; ++k) g[k] = t32[swzc(h0 + (k << 3), cd)];
    float fa[8], fb[8], oa[8], ob[8];
#pragma unroll
    for (int k = 0; k < 8; ++k) {
      fa[k] = bf2f(g[k]);
      fb[k] = bf2f(g[k] >> 16);
    }
    lift3f(fa, oa);
    lift3f(fb, ob);
#pragma unroll
    for (int k = 0; k < 8; ++k)
      t32[swzc(h0 + (k << 3), cd)] = pk2(oa[k], ob[k]);
  }
  __syncthreads();

  // ---- S3: fwd levels 7-8 (4 values @ stride 64), 32 threads ----
  if (tid < 32) {
    unsigned int g[4];
#pragma unroll
    for (int k = 0; k < 4; ++k) g[k] = t32[swzc(k << 6, tid)];
    float fa[4], fb[4];
#pragma unroll
    for (int k = 0; k < 4; ++k) {
      fa[k] = bf2f(g[k]);
      fb[k] = bf2f(g[k] >> 16);
    }
    const float aa0 = kNorm * (fa[0] + fa[1]), da0 = kNorm * (fa[0] - fa[1]);
    const float aa1 = kNorm * (fa[2] + fa[3]), da1 = kNorm * (fa[2] - fa[3]);
    const float ab0 = kNorm * (fb[0] + fb[1]), db0 = kNorm * (fb[0] - fb[1]);
    const float ab1 = kNorm * (fb[2] + fb[3]), db1 = kNorm * (fb[2] - fb[3]);
    t32[swzc(0, tid)] = pk2(kNorm * (aa0 + aa1), kNorm * (ab0 + ab1));
    t32[swzc(64, tid)] = pk2(da0, db0);
    t32[swzc(128, tid)] = pk2(kNorm * (aa0 - aa1), kNorm * (ab0 - ab1));
    t32[swzc(192, tid)] = pk2(da1, db1);
  }
  __syncthreads();

  // ---- GEMM + fused epilogue, per-wave 64-row strip ----
  // mfma_f32_16x16x32_bf16: A[m][k]: m=lane&15 (h), k=8*(lane>>4)+j (c)
  // D: col o'=lane&15, row = strip+16mt+4*(lane>>4)+reg
  // Per (mt, og): only acc_lo/acc_hi (8 regs) live -> no unified-RF spill.
  const int strip = (tid >> 6) << 6;
  const int l15 = tid & 15;
  const int l4 = (tid & 63) >> 4;
#pragma unroll 1
  for (int mt = 0; mt < 4; ++mt) {
    const int hh = strip + (mt << 4) + l15;
    const short8 a0 =
        *reinterpret_cast<const short8*>(&t32[swzc(hh, l4 << 2)]);
    const short8 a1 =
        *reinterpret_cast<const short8*>(&t32[swzc(hh, 16 + (l4 << 2))]);
    const int hb = strip + (mt << 4) + (l4 << 2);
    const uint4v vq = *reinterpret_cast<const uint4v*>(&vt[hb]);
    const uint4v tq = *reinterpret_cast<const uint4v*>(&vt[256 + hb]);
#pragma unroll
    for (int og = 0; og < 4; ++og) {
      const int o = (og << 4) + l15;  // p=0 col o, p=1 col 64+o
      const unsigned short* wr0 = wb + (o << 6) + (l4 << 3);         // p=0
      const unsigned short* wr1 = wb + 4096 + (o << 6) + (l4 << 3);  // p=1
      const short8 b0 = *reinterpret_cast<const short8*>(wr0);
      const short8 b1 = *reinterpret_cast<const short8*>(wr0 + 32);
      const short8 c0v = *reinterpret_cast<const short8*>(wr1);
      const short8 c1v = *reinterpret_cast<const short8*>(wr1 + 32);
      f32x4 accL = {0.f, 0.f, 0.f, 0.f};
      f32x4 accH = {0.f, 0.f, 0.f, 0.f};
      accL = __builtin_amdgcn_mfma_f32_16x16x32_bf16(a0, b0, accL, 0, 0, 0);
      accH = __builtin_amdgcn_mfma_f32_16x16x32_bf16(a0, c0v, accH, 0, 0, 0);
      accL = __builtin_amdgcn_mfma_f32_16x16x32_bf16(a1, b1, accL, 0, 0, 0);
      accH = __builtin_amdgcn_mfma_f32_16x16x32_bf16(a1, c1v, accH, 0, 0, 0);
#pragma unroll
      for (int r = 0; r < 4; ++r) {
        const float v0 = bf2f(vq[r]), v1 = bf2f(vq[r] >> 16);
        const float t0 = bf2f(tq[r]), t1 = bf2f(tq[r] >> 16);
        const float g0 = accL[r] * v0;
        const float g1 = accH[r] * v1;
        float rr = 0.f;
        const float q0 = fabsf(g0) - t0;
        if (q0 > 0.f) rr += copysignf(q0, g0);
        const float q1 = fabsf(g1) - t1;
        if (q1 > 0.f) rr += copysignf(q1, g1);
        t16[(swzc(hb + r, o >> 1) << 1) | (o & 1)] = f2bf(rr);
      }
    }
  }
  __syncthreads();

  // ---- inverse S3: levels 8,7 ----
  if (tid < 32) {
    unsigned int g[4];
#pragma unroll
    for (int k = 0; k < 4; ++k) g[k] = t32[swzc(k << 6, tid)];
    float fa[4], fb[4];
#pragma unroll
    for (int k = 0; k < 4; ++k) {
      fa[k] = bf2f(g[k]);
      fb[k] = bf2f(g[k] >> 16);
    }
    const float ua0 = kNorm * (fa[0] + fa[2]), ua1 = kNorm * (fa[0] - fa[2]);
    const float ub0 = kNorm * (fb[0] + fb[2]), ub1 = kNorm * (fb[0] - fb[2]);
    t32[swzc(0, tid)] = pk2(kNorm * (ua0 + fa[1]), kNorm * (ub0 + fb[1]));
    t32[swzc(64, tid)] = pk2(kNorm * (ua0 - fa[1]), kNorm * (ub0 - fb[1]));
    t32[swzc(128, tid)] = pk2(kNorm * (ua1 + fa[3]), kNorm * (ub1 + fb[3]));
    t32[swzc(192, tid)] = pk2(kNorm * (ua1 - fa[3]), kNorm * (ub1 - fb[3]));
  }
  __syncthreads();

  // ---- inverse S2: levels 6,5,4 ----
  if (tid < 128) {
    const int cd = tid & 31;
    const int h0 = (tid >> 5) << 6;
    unsigned int g[8];
#pragma unroll
    for (int k = 0; k < 8; ++k) g[k] = t32[swzc(h0 + (k << 3), cd)];
    float fa[8], fb[8], oa[8], ob[8];
#pragma unroll
    for (int k = 0; k < 8; ++k) {
      fa[k] = bf2f(g[k]);
      fb[k] = bf2f(g[k] >> 16);
    }
    ilift3f(fa, oa);
    ilift3f(fb, ob);
#pragma unroll
    for (int k = 0; k < 8; ++k)
      t32[swzc(h0 + (k << 3), cd)] = pk2(oa[k], ob[k]);
  }
  __syncthreads();

  // ---- inverse S1: levels 3,2,1 in registers + global store ----
#pragma unroll
  for (int it = 0; it < 4; ++it) {
    const int h0 = (o8 << 3) + (it << 6);
    unsigned int g[8];
#pragma unroll
    for (int j = 0; j < 8; ++j) g[j] = t32[swzc(h0 + j, cdw)];
    float fa[8], fb[8], oa[8], ob[8];
#pragma unroll
    for (int j = 0; j < 8; ++j) {
      fa[j] = bf2f(g[j]);
      fb[j] = bf2f(g[j] >> 16);
    }
    ilift3f(fa, oa);
    ilift3f(fb, ob);
    ushort8 sA, sB;
#pragma unroll
    for (int j = 0; j < 8; ++j) {
      sA[j] = f2bf(oa[j]);
      sB[j] = f2bf(ob[j]);
    }
    *reinterpret_cast<ushort8*>(base + ((size_t)c0 << 16) + h0) = sA;
    *reinterpret_cast<ushort8*>(base + ((size_t)(c0 + 1) << 16) + h0) = sB;
  }
}

// ---------------- Kernel 3: inverse Haar along W + residual add -------------
__global__ __launch_bounds__(256) void k_invW(const unsigned short* __restrict__ at,
                                              const float* __restrict__ x,
                                              float* __restrict__ y) {
  __shared__ float tile[256][33];  // 256 w (in-place order) x 32 h, pitch 33
  const int blk = blockIdx.x;      // img*8 + htile
  const int img = blk >> 3;
  const int h0 = (blk & 7) << 5;
  const int tid = threadIdx.x;
  const int g8 = tid >> 5;
  const int l = tid & 31;

  const unsigned short* __restrict__ base = at + ((size_t)img << 16) + h0;
#pragma unroll
  for (int k = 0; k < 32; ++k) {
    const int wr = (g8 << 5) + k;
    const int wp = ref2ip(wr);
    tile[wp][l] = bf2f(base[((size_t)wr << 8) + l]);
  }
  __syncthreads();

#pragma unroll
  for (int ls = 8; ls >= 1; --ls) {
    const int s = 1 << ls;
    const int hs = s >> 1;
    const int ppc = 256 >> ls;
    const int total = 32 * ppc;
    for (int idx = tid; idx < total; idx += 256) {
      const int hcq = idx & 31;
      const int i = idx >> 5;
      const int p0 = i * s;
      const float a = tile[p0][hcq];
      const float d = tile[p0 + hs][hcq];
      tile[p0][hcq] = kNorm * (a + d);
      tile[p0 + hs][hcq] = kNorm * (a - d);
    }
    __syncthreads();
  }

  const float* __restrict__ xs = x + ((size_t)img << 16) + ((size_t)h0 << 8);
  float* __restrict__ yd = y + ((size_t)img << 16) + ((size_t)h0 << 8);
#pragma unroll
  for (int j = 0; j < 32; ++j) {
    yd[(j << 8) + tid] = tile[tid][j] + xs[(j << 8) + tid];
  }
}

}  // namespace

extern "C" void kernel_launch(void* const* d_in, const int* in_sizes, int n_in,
                              void* d_out, int out_size, void* d_ws, size_t ws_size,
                              hipStream_t stream) {
  (void)in_sizes; (void)n_in; (void)out_size; (void)ws_size;
  const float* x  = (const float*)d_in[0];
  const float* vv = (const float*)d_in[1];
  const float* cw = (const float*)d_in[2];
  const float* tt = (const float*)d_in[3];
  float* y = (float*)d_out;
  unsigned short* ws = (unsigned short*)d_ws;      // 128 MiB bf16 slab
  unsigned short* wb = ws + ((size_t)64 << 20);    // bf16 weights (16 KiB)
  unsigned int* vpk = (unsigned int*)(ws + ((size_t)64 << 20) + 16384);
  unsigned int* tpk = vpk + 65536;                 // 256 KiB each

  k_prep<<<256, 256, 0, stream>>>(cw, vv, tt, wb, vpk, tpk);
  k_fwdW<<<8192, 256, 0, stream>>>(x, ws);
  k_mid <<<4096, 256, 0, stream>>>(ws, wb, vpk, tpk);
  k_invW<<<8192, 256, 0, stream>>>(ws, x, y);
}

// Round 8
// 286.420 us; speedup vs baseline: 1.6254x; 1.2037x over previous
//
#include <hip/hip_runtime.h>
#include <hip/hip_bf16.h>

// Problem: B=16, C=64, H=256, W=256, P=2
// y = haar2d_inv( sum_p softthr( (haar2d(x)*v_p) @ w_p^T, tau_p ) ) + x
//
// ws: bf16 (b,c,wref,h) slab (128 MiB) + bf16 weights + packed/permuted v,tau.
//   k_prep : conv_w->bf16; v,tau -> bf16x2 packed, [w][h_inplace] layout
//   k_fwdW : x(f32) -> Hw(x), transposed+subband-permuted bf16 store to ws
//   k_mid  : per (b,w) slab: staged-lifting Haar-H fwd -> MFMA mix -> staged
//            inverse -> store. h-major packed LDS tile, 6 barriers.
//            B-fragments hoisted ONCE per thread (mt-invariant; rounds 6/7
//            re-loaded them per mt and spilled ~180 MB scratch).
//            launch_bounds(256,3): ~170-reg unified cap, no spill, 3 blk/CU.
//   k_invW : ws -> Hw^{-1} + x -> y (f32, natural layout)

namespace {

constexpr float kNorm = 0.70710678118654752440f;

typedef __attribute__((ext_vector_type(8))) short short8;
typedef __attribute__((ext_vector_type(4))) float f32x4;
typedef __attribute__((ext_vector_type(8))) unsigned short ushort8;
typedef __attribute__((ext_vector_type(4))) unsigned int uint4v;

// in-place lifting position -> reference subband position (n=256, 8 levels)
__device__ __forceinline__ int ip2ref(int p) {
  if (p == 0) return 0;
  const int j = __builtin_ctz(p) + 1;
  return (256 >> j) + (p >> j);
}
// reference subband position -> in-place lifting position
__device__ __forceinline__ int ref2ip(int r) {
  if (r == 0) return 0;
  const int tb = 31 - __builtin_clz(r);
  const int j = 8 - tb;
  return ((r - (1 << tb)) << j) | (1 << (j - 1));
}

__device__ __forceinline__ unsigned short f2bf(float f) {  // f32->bf16 RN
  unsigned int u = __float_as_uint(f);
  u += 0x7FFFu + ((u >> 16) & 1u);
  return (unsigned short)(u >> 16);
}
__device__ __forceinline__ float bf2f(unsigned int u) {
  return __uint_as_float((u & 0xFFFFu) << 16);
}
__device__ __forceinline__ unsigned pk2(float lo, float hi) {
  return (unsigned)f2bf(lo) | ((unsigned)f2bf(hi) << 16);
}

// 3-level forward Haar lifting on 8 values (in-place position convention)
__device__ __forceinline__ void lift3f(const float f[8], float o[8]) {
  const float a0 = kNorm * (f[0] + f[1]), d10 = kNorm * (f[0] - f[1]);
  const float a1 = kNorm * (f[2] + f[3]), d11 = kNorm * (f[2] - f[3]);
  const float a2 = kNorm * (f[4] + f[5]), d12 = kNorm * (f[4] - f[5]);
  const float a3 = kNorm * (f[6] + f[7]), d13 = kNorm * (f[6] - f[7]);
  const float b0 = kNorm * (a0 + a1), d20 = kNorm * (a0 - a1);
  const float b1 = kNorm * (a2 + a3), d21 = kNorm * (a2 - a3);
  o[0] = kNorm * (b0 + b1);
  o[4] = kNorm * (b0 - b1);
  o[2] = d20; o[6] = d21;
  o[1] = d10; o[3] = d11; o[5] = d12; o[7] = d13;
}
// inverse of lift3f
__device__ __forceinline__ void ilift3f(const float f[8], float o[8]) {
  const float b0 = kNorm * (f[0] + f[4]), b1 = kNorm * (f[0] - f[4]);
  const float a0 = kNorm * (b0 + f[2]), a1 = kNorm * (b0 - f[2]);
  const float a2 = kNorm * (b1 + f[6]), a3 = kNorm * (b1 - f[6]);
  o[0] = kNorm * (a0 + f[1]); o[1] = kNorm * (a0 - f[1]);
  o[2] = kNorm * (a1 + f[3]); o[3] = kNorm * (a1 - f[3]);
  o[4] = kNorm * (a2 + f[5]); o[5] = kNorm * (a2 - f[5]);
  o[6] = kNorm * (a3 + f[7]); o[7] = kNorm * (a3 - f[7]);
}

// ---------------- Kernel 0: weights -> bf16; v,tau -> packed/permuted -------
__global__ __launch_bounds__(256) void k_prep(const float* __restrict__ cw,
                                              const float* __restrict__ vv,
                                              const float* __restrict__ tt,
                                              unsigned short* __restrict__ wb,
                                              unsigned int* __restrict__ vpk,
                                              unsigned int* __restrict__ tpk) {
  const int idx = blockIdx.x * 256 + threadIdx.x;  // 65536 = 256 w x 256 hp
  if (idx < 8192) wb[idx] = f2bf(cw[idx]);
  const int w = idx >> 8;
  const int hp = idx & 255;                 // in-place h position
  const int off = (ip2ref(hp) << 8) + w;    // reference coord
  vpk[idx] = pk2(vv[off], vv[65536 + off]);
  tpk[idx] = pk2(tt[off], tt[65536 + off]);
}

// ---------------- Kernel 1: forward Haar along W, transposed bf16 store -----
__global__ __launch_bounds__(256) void k_fwdW(const float* __restrict__ x,
                                              unsigned short* __restrict__ xt) {
  __shared__ float tile[32][257];  // 32 rows (h) x 256 cols (w), pitch 257
  const int blk = blockIdx.x;      // img*8 + htile
  const int img = blk >> 3;        // b*64 + c
  const int h0 = (blk & 7) << 5;
  const int tid = threadIdx.x;

  const float* __restrict__ src = x + ((size_t)img << 16) + ((size_t)h0 << 8);
#pragma unroll
  for (int j = 0; j < 32; ++j) tile[j][tid] = src[(j << 8) + tid];
  __syncthreads();

#pragma unroll
  for (int ls = 1; ls <= 8; ++ls) {
    const int s = 1 << ls;
    const int hs = s >> 1;
    const int ppr = 256 >> ls;
    const int total = 32 * ppr;
    for (int idx = tid; idx < total; idx += 256) {
      const int r = idx / ppr;
      const int i = idx - r * ppr;
      float* row = &tile[r][0];
      const int p0 = i * s;
      const float e = row[p0];
      const float o = row[p0 + hs];
      row[p0] = kNorm * (e + o);
      row[p0 + hs] = kNorm * (e - o);
    }
    __syncthreads();
  }

  // transposed bf16 write with in-place -> subband permutation: xt[img][wref][h]
  const int g8 = tid >> 5;
  const int l = tid & 31;
  unsigned short* __restrict__ dst = xt + ((size_t)img << 16) + h0;
#pragma unroll
  for (int k = 0; k < 32; ++k) {
    const int wp = g8 + (k << 3);
    const int wr = ip2ref(wp);
    dst[((size_t)wr << 8) + l] = f2bf(tile[l][wp]);
  }
}

// ---------------- Kernel 2: staged Haar-H + MFMA mix (h-major packed LDS) ---
// tile dword (h, cdw): dwidx = h*32 + ((cdw + 4*(h&7) + 8*((h>>3)&3)) & 31)
// Rotation keeps 4-dword alignment (b128-able) and makes every phase <=2-way.
__device__ __forceinline__ int swzc(int h, int cdw) {
  return (h << 5) | ((cdw + ((h & 7) << 2) + (((h >> 3) & 3) << 3)) & 31);
}

__global__ __launch_bounds__(256, 3) void k_mid(
    unsigned short* __restrict__ ws, const unsigned short* __restrict__ wb,
    const unsigned int* __restrict__ vpk, const unsigned int* __restrict__ tpk) {
  __shared__ unsigned int t32[8192];  // 32 KiB: [h=256][cdw=32] swizzled
  __shared__ unsigned int vt[512];    // [0..255]=v packed, [256..511]=tau packed
  unsigned short* t16 = reinterpret_cast<unsigned short*>(t32);

  const int blk = blockIdx.x;  // b*256 + w
  const int b = blk >> 8;
  const int w = blk & 255;
  const int tid = threadIdx.x;

  unsigned short* __restrict__ base = ws + ((size_t)b << 22) + ((size_t)w << 8);

  // stage v/tau (coalesced; already ip2ref-permuted by k_prep)
  vt[tid] = vpk[(w << 8) + tid];
  vt[256 + tid] = tpk[(w << 8) + tid];

  // ---- B-fragment preload: mt-invariant, load ONCE (64 VGPRs, on purpose).
  // B[k][n]: n=lane&15 (o'), k=8*(lane>>4)+j (c)
  const int l15 = tid & 15;
  const int l4 = (tid & 63) >> 4;
  short8 Bf[4][4];  // [og][b0,b1(p=0); c0,c1(p=1)] - fully unrolled -> regs
#pragma unroll
  for (int og = 0; og < 4; ++og) {
    const int o = (og << 4) + l15;
    const unsigned short* wr0 = wb + (o << 6) + (l4 << 3);         // p=0
    const unsigned short* wr1 = wb + 4096 + (o << 6) + (l4 << 3);  // p=1
    Bf[og][0] = *reinterpret_cast<const short8*>(wr0);
    Bf[og][1] = *reinterpret_cast<const short8*>(wr0 + 32);
    Bf[og][2] = *reinterpret_cast<const short8*>(wr1);
    Bf[og][3] = *reinterpret_cast<const short8*>(wr1 + 32);
  }

  // ---- S1: global->reg, fwd levels 1-3 in registers, write tile ----
  const int cdw = tid >> 3;  // 0..31 (channel pair)
  const int c0 = cdw << 1;
  const int o8 = tid & 7;
#pragma unroll
  for (int it = 0; it < 4; ++it) {
    const int h0 = (o8 << 3) + (it << 6);
    const ushort8 rA =
        *reinterpret_cast<const ushort8*>(base + ((size_t)c0 << 16) + h0);
    const ushort8 rB =
        *reinterpret_cast<const ushort8*>(base + ((size_t)(c0 + 1) << 16) + h0);
    float fa[8], fb[8], oa[8], ob[8];
#pragma unroll
    for (int j = 0; j < 8; ++j) {
      fa[j] = bf2f(rA[j]);
      fb[j] = bf2f(rB[j]);
    }
    lift3f(fa, oa);
    lift3f(fb, ob);
#pragma unroll
    for (int j = 0; j < 8; ++j) t32[swzc(h0 + j, cdw)] = pk2(oa[j], ob[j]);
  }
  __syncthreads();

  // ---- S2: fwd levels 4-6 (8 values @ stride 8), 128 threads ----
  if (tid < 128) {
    const int cd = tid & 31;
    const int h0 = (tid >> 5) << 6;
    unsigned int g[8];
#pragma unroll
    for (int k = 0; k < 8; ++k) g[k] = t32[swzc(h0 + (k << 3), cd)];
    float fa[8], fb[8], oa[8], ob[8];
#pragma unroll
    for (int k = 0; k < 8; ++k) {
      fa[k] = bf2f(g[k]);
      fb[k] = bf2f(g[k] >> 16);
    }
    lift3f(fa, oa);
    lift3f(fb, ob);
#pragma unroll
    for (int k = 0; k < 8; ++k)
      t32[swzc(h0 + (k << 3), cd)] = pk2(oa[k], ob[k]);
  }
  __syncthreads();

  // ---- S3: fwd levels 7-8 (4 values @ stride 64), 32 threads ----
  if (tid < 32) {
    unsigned int g[4];
#pragma unroll
    for (int k = 0; k < 4; ++k) g[k] = t32[swzc(k << 6, tid)];
    float fa[4], fb[4];
#pragma unroll
    for (int k = 0; k < 4; ++k) {
      fa[k] = bf2f(g[k]);
      fb[k] = bf2f(g[k] >> 16);
    }
    const float aa0 = kNorm * (fa[0] + fa[1]), da0 = kNorm * (fa[0] - fa[1]);
    const float aa1 = kNorm * (fa[2] + fa[3]), da1 = kNorm * (fa[2] - fa[3]);
    const float ab0 = kNorm * (fb[0] + fb[1]), db0 = kNorm * (fb[0] - fb[1]);
    const float ab1 = kNorm * (fb[2] + fb[3]), db1 = kNorm * (fb[2] - fb[3]);
    t32[swzc(0, tid)] = pk2(kNorm * (aa0 + aa1), kNorm * (ab0 + ab1));
    t32[swzc(64, tid)] = pk2(da0, db0);
    t32[swzc(128, tid)] = pk2(kNorm * (aa0 - aa1), kNorm * (ab0 - ab1));
    t32[swzc(192, tid)] = pk2(da1, db1);
  }
  __syncthreads();

  // ---- GEMM + fused epilogue, per-wave 64-row strip ----
  // mfma_f32_16x16x32_bf16: A[m][k]: m=lane&15 (h), k=8*(lane>>4)+j (c)
  // D: col o'=lane&15, row = strip+16mt+4*(lane>>4)+reg
  const int strip = (tid >> 6) << 6;
#pragma unroll 1
  for (int mt = 0; mt < 4; ++mt) {
    const int hh = strip + (mt << 4) + l15;
    const short8 a0 =
        *reinterpret_cast<const short8*>(&t32[swzc(hh, l4 << 2)]);
    const short8 a1 =
        *reinterpret_cast<const short8*>(&t32[swzc(hh, 16 + (l4 << 2))]);
    const int hb = strip + (mt << 4) + (l4 << 2);
    const uint4v vq = *reinterpret_cast<const uint4v*>(&vt[hb]);
    const uint4v tq = *reinterpret_cast<const uint4v*>(&vt[256 + hb]);
#pragma unroll
    for (int og = 0; og < 4; ++og) {
      const int o = (og << 4) + l15;  // p=0 col o, p=1 col 64+o
      f32x4 accL = {0.f, 0.f, 0.f, 0.f};
      f32x4 accH = {0.f, 0.f, 0.f, 0.f};
      accL = __builtin_amdgcn_mfma_f32_16x16x32_bf16(a0, Bf[og][0], accL, 0, 0, 0);
      accH = __builtin_amdgcn_mfma_f32_16x16x32_bf16(a0, Bf[og][2], accH, 0, 0, 0);
      accL = __builtin_amdgcn_mfma_f32_16x16x32_bf16(a1, Bf[og][1], accL, 0, 0, 0);
      accH = __builtin_amdgcn_mfma_f32_16x16x32_bf16(a1, Bf[og][3], accH, 0, 0, 0);
#pragma unroll
      for (int r = 0; r < 4; ++r) {
        const float v0 = bf2f(vq[r]), v1 = bf2f(vq[r] >> 16);
        const float t0 = bf2f(tq[r]), t1 = bf2f(tq[r] >> 16);
        const float g0 = accL[r] * v0;
        const float g1 = accH[r] * v1;
        float rr = 0.f;
        const float q0 = fabsf(g0) - t0;
        if (q0 > 0.f) rr += copysignf(q0, g0);
        const float q1 = fabsf(g1) - t1;
        if (q1 > 0.f) rr += copysignf(q1, g1);
        t16[(swzc(hb + r, o >> 1) << 1) | (o & 1)] = f2bf(rr);
      }
    }
  }
  __syncthreads();

  // ---- inverse S3: levels 8,7 ----
  if (tid < 32) {
    unsigned int g[4];
#pragma unroll
    for (int k = 0; k < 4; ++k) g[k] = t32[swzc(k << 6, tid)];
    float fa[4], fb[4];
#pragma unroll
    for (int k = 0; k < 4; ++k) {
      fa[k] = bf2f(g[k]);
      fb[k] = bf2f(g[k] >> 16);
    }
    const float ua0 = kNorm * (fa[0] + fa[2]), ua1 = kNorm * (fa[0] - fa[2]);
    const float ub0 = kNorm * (fb[0] + fb[2]), ub1 = kNorm * (fb[0] - fb[2]);
    t32[swzc(0, tid)] = pk2(kNorm * (ua0 + fa[1]), kNorm * (ub0 + fb[1]));
    t32[swzc(64, tid)] = pk2(kNorm * (ua0 - fa[1]), kNorm * (ub0 - fb[1]));
    t32[swzc(128, tid)] = pk2(kNorm * (ua1 + fa[3]), kNorm * (ub1 + fb[3]));
    t32[swzc(192, tid)] = pk2(kNorm * (ua1 - fa[3]), kNorm * (ub1 - fb[3]));
  }
  __syncthreads();

  // ---- inverse S2: levels 6,5,4 ----
  if (tid < 128) {
    const int cd = tid & 31;
    const int h0 = (tid >> 5) << 6;
    unsigned int g[8];
#pragma unroll
    for (int k = 0; k < 8; ++k) g[k] = t32[swzc(h0 + (k << 3), cd)];
    float fa[8], fb[8], oa[8], ob[8];
#pragma unroll
    for (int k = 0; k < 8; ++k) {
      fa[k] = bf2f(g[k]);
      fb[k] = bf2f(g[k] >> 16);
    }
    ilift3f(fa, oa);
    ilift3f(fb, ob);
#pragma unroll
    for (int k = 0; k < 8; ++k)
      t32[swzc(h0 + (k << 3), cd)] = pk2(oa[k], ob[k]);
  }
  __syncthreads();

  // ---- inverse S1: levels 3,2,1 in registers + global store ----
#pragma unroll
  for (int it = 0; it < 4; ++it) {
    const int h0 = (o8 << 3) + (it << 6);
    unsigned int g[8];
#pragma unroll
    for (int j = 0; j < 8; ++j) g[j] = t32[swzc(h0 + j, cdw)];
    float fa[8], fb[8], oa[8], ob[8];
#pragma unroll
    for (int j = 0; j < 8; ++j) {
      fa[j] = bf2f(g[j]);
      fb[j] = bf2f(g[j] >> 16);
    }
    ilift3f(fa, oa);
    ilift3f(fb, ob);
    ushort8 sA, sB;
#pragma unroll
    for (int j = 0; j < 8; ++j) {
      sA[j] = f2bf(oa[j]);
      sB[j] = f2bf(ob[j]);
    }
    *reinterpret_cast<ushort8*>(base + ((size_t)c0 << 16) + h0) = sA;
    *reinterpret_cast<ushort8*>(base + ((size_t)(c0 + 1) << 16) + h0) = sB;
  }
}

// ---------------- Kernel 3: inverse Haar along W + residual add -------------
__global__ __launch_bounds__(256) void k_invW(const unsigned short* __restrict__ at,
                                              const float* __restrict__ x,
                                              float* __restrict__ y) {
  __shared__ float tile[256][33];  // 256 w (in-place order) x 32 h, pitch 33
  const int blk = blockIdx.x;      // img*8 + htile
  const int img = blk >> 3;
  const int h0 = (blk & 7) << 5;
  const int tid = threadIdx.x;
  const int g8 = tid >> 5;
  const int l = tid & 31;

  const unsigned short* __restrict__ base = at + ((size_t)img << 16) + h0;
#pragma unroll
  for (int k = 0; k < 32; ++k) {
    const int wr = (g8 << 5) + k;
    const int wp = ref2ip(wr);
    tile[wp][l] = bf2f(base[((size_t)wr << 8) + l]);
  }
  __syncthreads();

#pragma unroll
  for (int ls = 8; ls >= 1; --ls) {
    const int s = 1 << ls;
    const int hs = s >> 1;
    const int ppc = 256 >> ls;
    const int total = 32 * ppc;
    for (int idx = tid; idx < total; idx += 256) {
      const int hcq = idx & 31;
      const int i = idx >> 5;
      const int p0 = i * s;
      const float a = tile[p0][hcq];
      const float d = tile[p0 + hs][hcq];
      tile[p0][hcq] = kNorm * (a + d);
      tile[p0 + hs][hcq] = kNorm * (a - d);
    }
    __syncthreads();
  }

  const float* __restrict__ xs = x + ((size_t)img << 16) + ((size_t)h0 << 8);
  float* __restrict__ yd = y + ((size_t)img << 16) + ((size_t)h0 << 8);
#pragma unroll
  for (int j = 0; j < 32; ++j) {
    yd[(j << 8) + tid] = tile[tid][j] + xs[(j << 8) + tid];
  }
}

}  // namespace

extern "C" void kernel_launch(void* const* d_in, const int* in_sizes, int n_in,
                              void* d_out, int out_size, void* d_ws, size_t ws_size,
                              hipStream_t stream) {
  (void)in_sizes; (void)n_in; (void)out_size; (void)ws_size;
  const float* x  = (const float*)d_in[0];
  const float* vv = (const float*)d_in[1];
  const float* cw = (const float*)d_in[2];
  const float* tt = (const float*)d_in[3];
  float* y = (float*)d_out;
  unsigned short* ws = (unsigned short*)d_ws;      // 128 MiB bf16 slab
  unsigned short* wb = ws + ((size_t)64 << 20);    // bf16 weights (16 KiB)
  unsigned int* vpk = (unsigned int*)(ws + ((size_t)64 << 20) + 16384);
  unsigned int* tpk = vpk + 65536;                 // 256 KiB each

  k_prep<<<256, 256, 0, stream>>>(cw, vv, tt, wb, vpk, tpk);
  k_fwdW<<<8192, 256, 0, stream>>>(x, ws);
  k_mid <<<4096, 256, 0, stream>>>(ws, wb, vpk, tpk);
  k_invW<<<8192, 256, 0, stream>>>(ws, x, y);
}